// Round 1
// 467.407 us; speedup vs baseline: 1.0745x; 1.0745x over previous
//
#include <hip/hip_runtime.h>

#define BT 16
#define NN 8192
#define FIN 128
#define FOUT 32
#define NB 512       // BT*FOUT
#define SPLITK 4
#define KSPAN (NN / SPLITK)   // 2048
#define BKK 64
#define PADK 72      // As row stride: 144 B -> 2-way (free) for write+read

typedef __attribute__((ext_vector_type(8))) short short8;
typedef __attribute__((ext_vector_type(4))) float float4v;

__device__ __forceinline__ float bf2f(unsigned short u) {
    unsigned v = ((unsigned)u) << 16;
    float f;
    __builtin_memcpy(&f, &v, 4);
    return f;
}
__device__ __forceinline__ unsigned short f2bf(float f) {
    unsigned u;
    __builtin_memcpy(&u, &f, 4);
    u += 0x7FFFu + ((u >> 16) & 1u);   // RNE
    return (unsigned short)(u >> 16);
}

// async global->LDS, 16 B per lane; LDS dest = wave-uniform base + lane*16
__device__ __forceinline__ void load_lds16(const unsigned short* g, unsigned short* l) {
    __builtin_amdgcn_global_load_lds((const __attribute__((address_space(1))) void*)g,
                                     (__attribute__((address_space(3))) void*)l, 16, 0, 0);
}

// ---------------------------------------------------------------------------
// Sniff bf16-vs-fp32 (proven R1/R2) + zero sumh[512].
// ---------------------------------------------------------------------------
__global__ void sniff_dtype(const unsigned* __restrict__ Wraw, unsigned* __restrict__ flag,
                            float* __restrict__ sumh) {
    int lane = threadIdx.x;
    unsigned u = Wraw[lane];
    float f = bf2f((unsigned short)(u & 0xFFFFu));
    float af = fabsf(f);
    bool plaus = (af > 1e-5f) && (af < 1e3f);
    unsigned long long msk = __ballot(plaus);
    if (lane == 0) flag[0] = (__popcll(msk) >= 32) ? 1u : 0u;
#pragma unroll
    for (int r = 0; r < 8; ++r) sumh[lane + 64 * r] = 0.f;
}

// ---------------------------------------------------------------------------
// K1: [0,128) zero s2 | [128,1152) h = inp @ W  (+ per-bt column sums of h)
// (pack pass deleted: adj is consumed directly by k2_fused)
// ---------------------------------------------------------------------------
__launch_bounds__(256)
__global__ void k1(const void* __restrict__ inp_raw, const void* __restrict__ W_raw,
                   unsigned short* __restrict__ Ht, float* __restrict__ sumh,
                   float4* __restrict__ s2v, const unsigned* __restrict__ flagp) {
    __shared__ __align__(16) unsigned short Wt[32 * 136];
    int bid = blockIdx.x;
    const int tid = threadIdx.x;

    if (bid < 128) {                 // ---- zero s2 (131072 floats = 32768 float4)
        float4 z; z.x = z.y = z.z = z.w = 0.f;
        s2v[bid * 256 + tid] = z;
        return;
    }
    bid -= 128;                      // ---- h-part (R2 k1 body, proven)
    const int bt = bid >> 6;
    const int j0 = (bid & 63) * 128;
    const bool isbf = (*flagp != 0u);

    if (isbf) {
        const unsigned short* Wb = (const unsigned short*)W_raw;
#pragma unroll
        for (int r = 0; r < 16; ++r) {
            int idx = tid + 256 * r, i = idx >> 5, o = idx & 31;
            Wt[o * 136 + i] = Wb[idx];
        }
    } else {
        const float* Wf = (const float*)W_raw;
#pragma unroll
        for (int r = 0; r < 16; ++r) {
            int idx = tid + 256 * r, i = idx >> 5, o = idx & 31;
            Wt[o * 136 + i] = f2bf(Wf[idx]);
        }
    }
    __syncthreads();

    const int lane = tid & 63, w = tid >> 6;
    const int m = lane & 15, q = lane >> 4;
    const int mt = (w & 1) * 16;
    const int nt = (w >> 1) * 64;

    float4v acc[4];
#pragma unroll
    for (int c = 0; c < 4; ++c) { float4v z = {0.f, 0.f, 0.f, 0.f}; acc[c] = z; }

#pragma unroll
    for (int kstep = 0; kstep < 4; ++kstep) {
        short8 af = *(const short8*)&Wt[(mt + m) * 136 + kstep * 32 + q * 8];
#pragma unroll
        for (int c = 0; c < 4; ++c) {
            int j = j0 + nt + c * 16 + m;
            short8 bfrag;
            if (isbf) {
                bfrag = *(const short8*)((const unsigned short*)inp_raw +
                        ((size_t)bt * NN + j) * FIN + kstep * 32 + q * 8);
            } else {
                const float* fp = (const float*)inp_raw + ((size_t)bt * NN + j) * FIN + kstep * 32 + q * 8;
                float4 f0 = *(const float4*)fp;
                float4 f1 = *(const float4*)(fp + 4);
                union { unsigned short u[8]; short8 v; } t;
                t.u[0] = f2bf(f0.x); t.u[1] = f2bf(f0.y); t.u[2] = f2bf(f0.z); t.u[3] = f2bf(f0.w);
                t.u[4] = f2bf(f1.x); t.u[5] = f2bf(f1.y); t.u[6] = f2bf(f1.z); t.u[7] = f2bf(f1.w);
                bfrag = t.v;
            }
            acc[c] = __builtin_amdgcn_mfma_f32_16x16x32_bf16(af, bfrag, acc[c], 0, 0, 0);
        }
    }

#pragma unroll
    for (int c = 0; c < 4; ++c) {
#pragma unroll
        for (int e = 0; e < 4; ++e) {
            int o = mt + q * 4 + e;
            int j = j0 + nt + c * 16 + m;
            Ht[(size_t)(bt * FOUT + o) * NN + j] = f2bf(acc[c][e]);
        }
    }
#pragma unroll
    for (int e = 0; e < 4; ++e) {
        float s = acc[0][e] + acc[1][e] + acc[2][e] + acc[3][e];
        s += __shfl_xor(s, 1); s += __shfl_xor(s, 2);
        s += __shfl_xor(s, 4); s += __shfl_xor(s, 8);
        if (m == 0) atomicAdd(&sumh[bt * FOUT + mt + q * 4 + e], s);
    }
}

// ---------------------------------------------------------------------------
// K2 fused: s2[bt][i] += sum_o a2[i,o] * (sum_k (adj[k][i]>0) * Ht[bt*32+o][k])
// Tile: 64(i) x 512(all n) x BK=64, split-K=4 -> 512 blocks, 8 waves, 2/CU.
// adj read ONCE chip-wide, transposed via reg-staging (8 coalesced dwords per
// thread -> one contiguous b128 into padded As). B staged via 8x
// global_load_lds/wave with XOR source-swizzle (proven pattern). adj regs for
// step t+1 prefetched during step t. XCD swizzle clusters same-z blocks so
// each XCD's 2 MB Ht k-slice stays in its private L2.
// ---------------------------------------------------------------------------
__launch_bounds__(512, 4)
__global__ void k2_fused(const int* __restrict__ adj, const unsigned short* __restrict__ Ht,
                         const void* __restrict__ a_raw, float* __restrict__ s2,
                         const unsigned* __restrict__ flagp) {
    __shared__ __align__(16) unsigned short As[64 * PADK];   // 9.2 KB
    __shared__ __align__(16) unsigned short Bs[512 * 64];    // 64 KB
    const int tid = threadIdx.x;
    const int lane = tid & 63;
    const int w = tid >> 6;              // wave 0..7, owns n in [w*64, w*64+64)
    const int m = lane & 15, q = lane >> 4;
    const int wn = w * 64;

    // XCD-aware decomposition: bid&7 ~ XCD; 2 XCDs per z-slice.
    const int bid = blockIdx.x;
    const int xcd = bid & 7;
    const int z = xcd >> 1;                          // 0..3
    const int ib = (bid >> 3) | ((xcd & 1) << 6);    // 0..127 (bijective)
    const int i0 = ib * 64;
    const int zbase = z * KSPAN;

    // per-lane DMA source offsets (halfword units) for the 8 calls/wave:
    // unit u covers LDS slot (n = u>>3, kb = u&7); source octet kb ^ (n&7).
    int boff[8];
#pragma unroll
    for (int c = 0; c < 8; ++c) {
        int u = (w * 8 + c) * 64 + lane;
        int n = u >> 3;
        int kbs = (u & 7) ^ (n & 7);
        boff[c] = n * NN + kbs * 8;
    }

    // A staging: thread covers column i = i0+lane, k-octet kh = w.
    const int si = lane;
    const int kh = w;
    const int* gcol = adj + (size_t)(zbase + kh * 8) * NN + i0 + si;

    float4v acc[4][4];
#pragma unroll
    for (int r = 0; r < 4; ++r)
#pragma unroll
        for (int c = 0; c < 4; ++c) { float4v zz = {0.f, 0.f, 0.f, 0.f}; acc[r][c] = zz; }

    // prologue: adj regs for step 0
    int av[8];
#pragma unroll
    for (int kk = 0; kk < 8; ++kk) av[kk] = gcol[(size_t)kk * NN];

    for (int ks0 = 0; ks0 < KSPAN; ks0 += BKK) {
        const int k0 = zbase + ks0;
        __syncthreads();                      // prev compute done; LDS writable
        // ---- B: 8 DMA calls/wave, LDS dest wave-uniform base + lane*16
#pragma unroll
        for (int c = 0; c < 8; ++c)
            load_lds16(Ht + boff[c] + k0, &Bs[(w * 8 + c) * 512]);
        // ---- A: convert adj regs -> bf16 {0,1}, one contiguous b128/thread
        {
            unsigned d[4];
#pragma unroll
            for (int p = 0; p < 4; ++p) {
                unsigned lo = (av[2 * p]     > 0) ? 0x3F80u     : 0u;
                unsigned hi = (av[2 * p + 1] > 0) ? 0x3F800000u : 0u;
                d[p] = lo | hi;
            }
            int4 t;
            t.x = (int)d[0]; t.y = (int)d[1]; t.z = (int)d[2]; t.w = (int)d[3];
            *(int4*)&As[si * PADK + kh * 8] = t;
        }
        // ---- prefetch next step's adj into regs (hidden under this compute)
        if (ks0 + BKK < KSPAN) {
#pragma unroll
            for (int kk = 0; kk < 8; ++kk)
                av[kk] = gcol[(size_t)(ks0 + BKK + kk) * NN];
        }
        __syncthreads();                      // vmcnt(0)+lgkm drain: LDS ready
        // ---- compute: 2 K-substeps x 4x4 frags
#pragma unroll
        for (int ks = 0; ks < 2; ++ks) {
            short8 af[4];
#pragma unroll
            for (int r = 0; r < 4; ++r)
                af[r] = *(const short8*)&As[(r * 16 + m) * PADK + ks * 32 + q * 8];
#pragma unroll
            for (int c = 0; c < 4; ++c) {
                int row = wn + c * 16 + m;
                int kbs = (ks * 4 + q) ^ (m & 7);   // row&7 == m&7
                short8 bfr = *(const short8*)&Bs[row * 64 + kbs * 8];
#pragma unroll
                for (int r = 0; r < 4; ++r)
                    acc[r][c] = __builtin_amdgcn_mfma_f32_16x16x32_bf16(af[r], bfr, acc[r][c], 0, 0, 0);
            }
        }
    }

    // ---- fused epilogue: s2 partial = sum_o nbr*a2, m-lane reduce, atomic
    const bool isbf = (*flagp != 0u);
    const int btA = wn >> 5;                  // = 2*w
#pragma unroll
    for (int r = 0; r < 4; ++r) {
#pragma unroll
        for (int e = 0; e < 4; ++e) {
            int gi = i0 + r * 16 + q * 4 + e;
            float a2m, a2m16;
            if (isbf) {
                const unsigned short* ab = (const unsigned short*)a_raw;
                a2m   = bf2f(ab[(size_t)(FOUT + m) * NN + gi]);
                a2m16 = bf2f(ab[(size_t)(FOUT + 16 + m) * NN + gi]);
            } else {
                const float* afp = (const float*)a_raw;
                a2m   = afp[(size_t)(FOUT + m) * NN + gi];
                a2m16 = afp[(size_t)(FOUT + 16 + m) * NN + gi];
            }
            float sA = acc[r][0][e] * a2m + acc[r][1][e] * a2m16;
            float sB = acc[r][2][e] * a2m + acc[r][3][e] * a2m16;
            sA += __shfl_xor(sA, 1); sA += __shfl_xor(sA, 2);
            sA += __shfl_xor(sA, 4); sA += __shfl_xor(sA, 8);
            sB += __shfl_xor(sB, 1); sB += __shfl_xor(sB, 2);
            sB += __shfl_xor(sB, 4); sB += __shfl_xor(sB, 8);
            if (m == 0) {
                atomicAdd(&s2[(size_t)btA * NN + gi], sA);
                atomicAdd(&s2[(size_t)(btA + 1) * NN + gi], sB);
            }
        }
    }
}

// ---------------------------------------------------------------------------
// K3: s = s2 + sum_o h*a1 ; out = relu(s * sumh[bt,:])
// ---------------------------------------------------------------------------
__launch_bounds__(256)
__global__ void k3_out(const unsigned short* __restrict__ Ht, const float* __restrict__ s2,
                       const float* __restrict__ sumh, const void* __restrict__ a_raw,
                       void* __restrict__ out_raw, const unsigned* __restrict__ flagp) {
    const int i = blockIdx.x * 256 + threadIdx.x;
    const int bt = blockIdx.y;
    const bool isbf = (*flagp != 0u);

    float s = s2[(size_t)bt * NN + i];
    if (isbf) {
        const unsigned short* ab = (const unsigned short*)a_raw;
#pragma unroll
        for (int o = 0; o < 32; ++o) {
            float h = bf2f(Ht[(size_t)(bt * FOUT + o) * NN + i]);
            s += h * bf2f(ab[(size_t)o * NN + i]);
        }
    } else {
        const float* afp = (const float*)a_raw;
#pragma unroll
        for (int o = 0; o < 32; ++o) {
            float h = bf2f(Ht[(size_t)(bt * FOUT + o) * NN + i]);
            s += h * afp[(size_t)o * NN + i];
        }
    }

    float ov[32];
#pragma unroll
    for (int o = 0; o < 32; ++o) ov[o] = fmaxf(s * sumh[bt * FOUT + o], 0.f);

    size_t ob = ((size_t)bt * NN + i) * FOUT;
    if (isbf) {
        unsigned short* o16 = (unsigned short*)out_raw + ob;
#pragma unroll
        for (int c = 0; c < 8; ++c) {
            ushort4 p;
            p.x = f2bf(ov[c * 4 + 0]); p.y = f2bf(ov[c * 4 + 1]);
            p.z = f2bf(ov[c * 4 + 2]); p.w = f2bf(ov[c * 4 + 3]);
            *(ushort4*)(o16 + c * 4) = p;
        }
    } else {
        float* of = (float*)out_raw + ob;
#pragma unroll
        for (int c = 0; c < 8; ++c) {
            float4 v;
            v.x = ov[c * 4 + 0]; v.y = ov[c * 4 + 1]; v.z = ov[c * 4 + 2]; v.w = ov[c * 4 + 3];
            *(float4*)(of + c * 4) = v;
        }
    }
}

// ---------------------------------------------------------------------------
extern "C" void kernel_launch(void* const* d_in, const int* in_sizes, int n_in,
                              void* d_out, int out_size, void* d_ws, size_t ws_size,
                              hipStream_t stream) {
    const void* inp = d_in[0];
    const int* adj = (const int*)d_in[1];
    const void* W = d_in[2];
    const void* a = d_in[3];

    char* ws = (char*)d_ws;
    unsigned short* Ht = (unsigned short*)ws;                    // 8 MB
    unsigned* flag = (unsigned*)(ws + 8388608);                  // 4 B
    float* s2 = (float*)(ws + 8388608 + 4096);                   // 512 KB (16B aligned)
    float* sumh = (float*)(ws + 8388608 + 4096 + 524288);        // 2 KB

    sniff_dtype<<<1, 64, 0, stream>>>((const unsigned*)W, flag, sumh);
    k1<<<1152, 256, 0, stream>>>(inp, W, Ht, sumh, (float4*)s2, flag);
    k2_fused<<<512, 512, 0, stream>>>(adj, Ht, a, s2, flag);
    k3_out<<<dim3(NN / 256, BT), 256, 0, stream>>>(Ht, s2, sumh, a, d_out, flag);
}